// Round 1
// baseline (325.145 us; speedup 1.0000x reference)
//
#include <hip/hip_runtime.h>

#define CLIP_HI (1.0f - 1e-6f)

__device__ __forceinline__ float tri_(float x) {
    return 2.0f * fabsf(x * 0.5f - floorf(x * 0.5f + 0.5f));
}

__device__ __forceinline__ float clamp01(float x) {
    return fminf(fmaxf(x, 0.0f), CLIP_HI);
}

// 2D bilinear lookup, table shape (U,V,C), row-major. NORM => apply tri() to
// each fetched table value BEFORE blending (matches reference t = tri(table)).
template <int U, int V, int C, bool NORM>
__device__ __forceinline__ void grid2d_bilinear(const float* __restrict__ t,
                                                float uc, float vc, float* out) {
    float u = clamp01(uc) * (float)(U - 1);
    float v = clamp01(vc) * (float)(V - 1);
    float u0f = floorf(u), v0f = floorf(v);
    float fu = u - u0f, fv = v - v0f;
    int u0 = (int)u0f, v0 = (int)v0f;
    int u1 = min(u0 + 1, U - 1);
    int v1 = min(v0 + 1, V - 1);
    float w00 = (1.0f - fu) * (1.0f - fv);
    float w10 = fu * (1.0f - fv);
    float w01 = (1.0f - fu) * fv;
    float w11 = fu * fv;
    if constexpr (C == 4) {
        const float4* t4 = (const float4*)t;
        float4 a = t4[u0 * V + v0];
        float4 b = t4[u1 * V + v0];
        float4 c = t4[u0 * V + v1];
        float4 d = t4[u1 * V + v1];
        if (NORM) {
            a.x = tri_(a.x); a.y = tri_(a.y); a.z = tri_(a.z); a.w = tri_(a.w);
            b.x = tri_(b.x); b.y = tri_(b.y); b.z = tri_(b.z); b.w = tri_(b.w);
            c.x = tri_(c.x); c.y = tri_(c.y); c.z = tri_(c.z); c.w = tri_(c.w);
            d.x = tri_(d.x); d.y = tri_(d.y); d.z = tri_(d.z); d.w = tri_(d.w);
        }
        out[0] = a.x * w00 + b.x * w10 + c.x * w01 + d.x * w11;
        out[1] = a.y * w00 + b.y * w10 + c.y * w01 + d.y * w11;
        out[2] = a.z * w00 + b.z * w10 + c.z * w01 + d.z * w11;
        out[3] = a.w * w00 + b.w * w10 + c.w * w01 + d.w * w11;
    } else {
        const float* p00 = t + (u0 * V + v0) * C;
        const float* p10 = t + (u1 * V + v0) * C;
        const float* p01 = t + (u0 * V + v1) * C;
        const float* p11 = t + (u1 * V + v1) * C;
#pragma unroll
        for (int c = 0; c < C; ++c) {
            float a = p00[c], b = p10[c], cc = p01[c], d = p11[c];
            if (NORM) { a = tri_(a); b = tri_(b); cc = tri_(cc); d = tri_(d); }
            out[c] = a * w00 + b * w10 + cc * w01 + d * w11;
        }
    }
}

__global__ __launch_bounds__(256) void DisneyNet_kernel(
    const float* __restrict__ roughNoh,
    const float* __restrict__ anisoToh,
    const float* __restrict__ nDotLV,
    const float* __restrict__ metalLoh,
    const float* __restrict__ subCg,
    const float* __restrict__ spst,
    const float* __restrict__ shst,
    const float* __restrict__ lumCs,
    const float* __restrict__ tabRAEnc,   // (2048,2048,2)
    const float* __restrict__ tabCgEnc,   // (2048,1)
    const float* __restrict__ tabRSEnc,   // (64,64,3)
    const float* __restrict__ tabRADec,   // (48,48,3)
    const float* __restrict__ tabCgDec,   // (96,2)
    const float* __restrict__ tabLVR,     // (32,32,1)
    const float* __restrict__ tabLV,      // (32,32,4)
    const float* __restrict__ tabNHL,     // (32,32,4)
    float* __restrict__ out,
    int n)
{
    int i = blockIdx.x * blockDim.x + threadIdx.x;
    if (i >= n) return;

    float2 rN  = ((const float2*)roughNoh)[i];
    float2 aT  = ((const float2*)anisoToh)[i];
    float2 nLV = ((const float2*)nDotLV)[i];
    float2 mL  = ((const float2*)metalLoh)[i];
    float2 sC  = ((const float2*)subCg)[i];
    float2 sp  = ((const float2*)spst)[i];
    float2 sh  = ((const float2*)shst)[i];
    float2 lC  = ((const float2*)lumCs)[i];

    // ra = grid2d(raIn, tabRAEnc, nearest, tri). raIn = (roughNoh0, anisoToh0)
    float ra0, ra1;
    {
        float u = clamp01(rN.x) * 2047.0f;
        float v = clamp01(aT.x) * 2047.0f;
        int ui = (int)rintf(u);   // jnp.round = half-to-even = v_rndne
        int vi = (int)rintf(v);
        float2 t = ((const float2*)tabRAEnc)[ui * 2048 + vi];
        ra0 = tri_(t.x);
        ra1 = tri_(t.y);
    }

    // cg = grid1d(subCg1, tabCgEnc (2048,1), nearest, tri)
    float cg;
    {
        float u = clamp01(sC.y) * 2047.0f;
        int ui = (int)rintf(u);
        cg = tri_(tabCgEnc[ui]);
    }

    // rsEnc = grid2d((roughNoh0, subCg0), tabRSEnc (64,64,3), bilinear, tri)
    float rs[3];
    grid2d_bilinear<64, 64, 3, true>(tabRSEnc, rN.x, sC.x, rs);

    // raCoefs = grid2d(ra, tabRADec (48,48,3), bilinear, no-norm)
    float raC[3];
    grid2d_bilinear<48, 48, 3, false>(tabRADec, ra0, ra1, raC);

    // cgCoefs = grid1d(cg, tabCgDec (96,2), bilinear, no-norm)
    float cgC0, cgC1;
    {
        float u = clamp01(cg) * 95.0f;
        float u0f = floorf(u);
        float fu = u - u0f;
        int u0 = (int)u0f;
        int u1 = min(u0 + 1, 95);
        float2 a = ((const float2*)tabCgDec)[u0];
        float2 b = ((const float2*)tabCgDec)[u1];
        cgC0 = a.x * (1.0f - fu) + b.x * fu;
        cgC1 = a.y * (1.0f - fu) + b.y * fu;
    }

    // vTerm = grid2d((nDotLV0*nDotLV1, ra0), tabLVR (32,32,1), bilinear, tri)
    float vTerm;
    grid2d_bilinear<32, 32, 1, true>(tabLVR, nLV.x * nLV.y, ra0, &vTerm);

    // nlvCoefs = grid2d(nDotLV, tabLV (32,32,4), bilinear, tri)
    float nlv[4];
    grid2d_bilinear<32, 32, 4, true>(tabLV, nLV.x, nLV.y, nlv);

    // nhlCoefs = grid2d((metalLoh1, nDotLV0), tabNHL (32,32,4), bilinear, tri)
    float nhl[4];
    grid2d_bilinear<32, 32, 4, true>(tabNHL, mL.y, nLV.x, nhl);

    float met = mL.x;
    float om  = 1.0f - met;
    float cd  = om * lC.x;
    float cm0 = sp.x * 0.1f * om * sp.y + met * lC.x;
    float cm1 = sp.x * 0.1f * om * (1.0f - sp.y);
    float cs0 = sh.x * om * sh.y;
    float cs1 = sh.x * om * (1.0f - sh.y);
    float cc  = 0.0625f * lC.y;          // 0.25*0.25

    float rsCd0 = rs[0] * cd;
    float rsCd1 = rs[1] * cd;
    float rsCd2 = rs[2] * cd;

    float noh2 = rN.y * rN.y;
    float den  = raC[0] * aT.y * aT.y + raC[1] * noh2 + raC[2];
    float dTerm = 0.25f / (nLV.y * den * den);

    float x = rsCd0 * mL.y * nlv[1] + rsCd1 * nlv[2] + rsCd2 * nlv[3]
            + cm0 * vTerm * nhl[2] * dTerm + cs0 * nhl[0];

    float y = ((1.0f - cm1) * nhl[3] + cm1) * vTerm * dTerm
            + cs1 * nhl[0]
            + cc * nhl[1] * nlv[0] / (nLV.y * (cgC0 * noh2 + cgC1));

    ((float2*)out)[i] = make_float2(x, y);
}

extern "C" void kernel_launch(void* const* d_in, const int* in_sizes, int n_in,
                              void* d_out, int out_size, void* d_ws, size_t ws_size,
                              hipStream_t stream) {
    // setup_inputs() order:
    // 0 roughNoh, 1 anisoToh, 2 nDotLV, 3 tDotLV (UNUSED), 4 metalLoh,
    // 5 subCg, 6 spst, 7 shst, 8 lumCs,
    // 9 tabRAEnc, 10 tabCgEnc, 11 tabRSEnc, 12 tabRADec, 13 tabCgDec,
    // 14 tabLVR, 15 tabLV, 16 tabNHL
    const float* roughNoh = (const float*)d_in[0];
    const float* anisoToh = (const float*)d_in[1];
    const float* nDotLV   = (const float*)d_in[2];
    const float* metalLoh = (const float*)d_in[4];
    const float* subCg    = (const float*)d_in[5];
    const float* spst     = (const float*)d_in[6];
    const float* shst     = (const float*)d_in[7];
    const float* lumCs    = (const float*)d_in[8];
    const float* tabRAEnc = (const float*)d_in[9];
    const float* tabCgEnc = (const float*)d_in[10];
    const float* tabRSEnc = (const float*)d_in[11];
    const float* tabRADec = (const float*)d_in[12];
    const float* tabCgDec = (const float*)d_in[13];
    const float* tabLVR   = (const float*)d_in[14];
    const float* tabLV    = (const float*)d_in[15];
    const float* tabNHL   = (const float*)d_in[16];

    int n = in_sizes[0] / 2;   // (N,2)
    float* out = (float*)d_out;

    int block = 256;
    int grid = (n + block - 1) / block;
    DisneyNet_kernel<<<grid, block, 0, stream>>>(
        roughNoh, anisoToh, nDotLV, metalLoh, subCg, spst, shst, lumCs,
        tabRAEnc, tabCgEnc, tabRSEnc, tabRADec, tabCgDec, tabLVR, tabLV, tabNHL,
        out, n);
}

// Round 2
// 290.181 us; speedup vs baseline: 1.1205x; 1.1205x over previous
//
#include <hip/hip_runtime.h>

#define CLIP_HI (1.0f - 1e-6f)

__device__ __forceinline__ float tri_(float x) {
    return 2.0f * fabsf(x * 0.5f - floorf(x * 0.5f + 0.5f));
}

__device__ __forceinline__ float clamp01(float x) {
    return fminf(fmaxf(x, 0.0f), CLIP_HI);
}

// Bilinear index/weight helper for a (U,V,*) table.
struct BW {
    int i00, i10, i01, i11;
    float w00, w10, w01, w11;
};

template <int U, int V>
__device__ __forceinline__ BW bw2d(float uc, float vc) {
    float u = clamp01(uc) * (float)(U - 1);
    float v = clamp01(vc) * (float)(V - 1);
    float u0f = floorf(u), v0f = floorf(v);
    float fu = u - u0f, fv = v - v0f;
    int u0 = (int)u0f, v0 = (int)v0f;
    int u1 = min(u0 + 1, U - 1);
    int v1 = min(v0 + 1, V - 1);
    BW r;
    r.i00 = u0 * V + v0;
    r.i10 = u1 * V + v0;
    r.i01 = u0 * V + v1;
    r.i11 = u1 * V + v1;
    float gu = 1.0f - fu, gv = 1.0f - fv;
    r.w00 = gu * gv;
    r.w10 = fu * gv;
    r.w01 = gu * fv;
    r.w11 = fu * fv;
    return r;
}

// Prep: repack tabRSEnc (64,64,3) -> (64,64,4) float4 in d_ws, tri() applied.
__global__ __launch_bounds__(256) void prep_rs_kernel(const float* __restrict__ t,
                                                      float4* __restrict__ o) {
    int j = blockIdx.x * 256 + threadIdx.x;
    if (j < 64 * 64) {
        float a = tri_(t[j * 3 + 0]);
        float b = tri_(t[j * 3 + 1]);
        float c = tri_(t[j * 3 + 2]);
        o[j] = make_float4(a, b, c, 0.0f);
    }
}

template <bool USE_WS>
__global__ __launch_bounds__(1024, 8) void disney_main(
    const float* __restrict__ roughNoh,
    const float* __restrict__ anisoToh,
    const float* __restrict__ nDotLV,
    const float* __restrict__ metalLoh,
    const float* __restrict__ subCg,
    const float* __restrict__ spst,
    const float* __restrict__ shst,
    const float* __restrict__ lumCs,
    const float* __restrict__ tabRAEnc,   // (2048,2048,2) global gather
    const float* __restrict__ tabCgEnc,   // (2048,1)      global gather
    const float* __restrict__ tabRSEnc,   // (64,64,3)     fallback path
    const float4* __restrict__ rsPacked,  // (64,64,4) in d_ws, tri'd
    const float* __restrict__ tabRADec,   // (48,48,3) -> LDS
    const float* __restrict__ tabCgDec,   // (96,2)    -> LDS
    const float* __restrict__ tabLVR,     // (32,32,1) -> LDS (tri'd)
    const float* __restrict__ tabLV,      // (32,32,4) -> LDS (tri'd)
    const float* __restrict__ tabNHL,     // (32,32,4) -> LDS (tri'd)
    float* __restrict__ out,
    int n)
{
    // 65280 B total: 2 blocks/CU at 160 KiB LDS -> 32 waves/CU.
    __shared__ float  sRADec[48 * 48 * 3];   // 27648 B
    __shared__ float2 sCgDec[96];            //   768 B
    __shared__ float  sLVR[1024];            //  4096 B
    __shared__ float4 sLV[1024];             // 16384 B
    __shared__ float4 sNHL[1024];            // 16384 B

    int tid = threadIdx.x;

    // ---- stage tables into LDS (tri folded in for normalized tables) ----
    for (int j = tid; j < 48 * 48 * 3; j += 1024) sRADec[j] = tabRADec[j];
    if (tid < 96) sCgDec[tid] = ((const float2*)tabCgDec)[tid];
    sLVR[tid] = tri_(tabLVR[tid]);
    {
        float4 v = ((const float4*)tabLV)[tid];
        sLV[tid] = make_float4(tri_(v.x), tri_(v.y), tri_(v.z), tri_(v.w));
    }
    {
        float4 v = ((const float4*)tabNHL)[tid];
        sNHL[tid] = make_float4(tri_(v.x), tri_(v.y), tri_(v.z), tri_(v.w));
    }
    __syncthreads();

    int i = blockIdx.x * 1024 + tid;
    if (i >= n) return;

    float2 rN  = ((const float2*)roughNoh)[i];
    float2 aT  = ((const float2*)anisoToh)[i];
    float2 nLV = ((const float2*)nDotLV)[i];
    float2 mL  = ((const float2*)metalLoh)[i];
    float2 sC  = ((const float2*)subCg)[i];
    float2 sp  = ((const float2*)spst)[i];
    float2 sh  = ((const float2*)shst)[i];
    float2 lC  = ((const float2*)lumCs)[i];

    // ra = nearest(tabRAEnc, (roughNoh0, anisoToh0)), tri'd. Global gather (33.5 MB).
    float ra0, ra1;
    {
        int ui = (int)rintf(clamp01(rN.x) * 2047.0f);  // jnp.round = half-to-even
        int vi = (int)rintf(clamp01(aT.x) * 2047.0f);
        float2 t = ((const float2*)tabRAEnc)[ui * 2048 + vi];
        ra0 = tri_(t.x);
        ra1 = tri_(t.y);
    }

    // cg = nearest(tabCgEnc, subCg1), tri'd. Global gather (8 KB, L1).
    float cg;
    {
        int ui = (int)rintf(clamp01(sC.y) * 2047.0f);
        cg = tri_(tabCgEnc[ui]);
    }

    // rsEnc = bilinear(tabRSEnc tri'd, (roughNoh0, subCg0))
    float rs0, rs1, rs2;
    {
        BW b = bw2d<64, 64>(rN.x, sC.x);
        if constexpr (USE_WS) {
            float4 a = rsPacked[b.i00];
            float4 c = rsPacked[b.i10];
            float4 d = rsPacked[b.i01];
            float4 e = rsPacked[b.i11];
            rs0 = a.x * b.w00 + c.x * b.w10 + d.x * b.w01 + e.x * b.w11;
            rs1 = a.y * b.w00 + c.y * b.w10 + d.y * b.w01 + e.y * b.w11;
            rs2 = a.z * b.w00 + c.z * b.w10 + d.z * b.w01 + e.z * b.w11;
        } else {
            const float* p00 = tabRSEnc + b.i00 * 3;
            const float* p10 = tabRSEnc + b.i10 * 3;
            const float* p01 = tabRSEnc + b.i01 * 3;
            const float* p11 = tabRSEnc + b.i11 * 3;
            float o[3];
#pragma unroll
            for (int c = 0; c < 3; ++c)
                o[c] = tri_(p00[c]) * b.w00 + tri_(p10[c]) * b.w10 +
                       tri_(p01[c]) * b.w01 + tri_(p11[c]) * b.w11;
            rs0 = o[0]; rs1 = o[1]; rs2 = o[2];
        }
    }

    // raCoefs = bilinear(tabRADec, ra) — LDS, no tri.
    float raC0, raC1, raC2;
    {
        BW b = bw2d<48, 48>(ra0, ra1);
        const float* p00 = &sRADec[b.i00 * 3];
        const float* p10 = &sRADec[b.i10 * 3];
        const float* p01 = &sRADec[b.i01 * 3];
        const float* p11 = &sRADec[b.i11 * 3];
        raC0 = p00[0] * b.w00 + p10[0] * b.w10 + p01[0] * b.w01 + p11[0] * b.w11;
        raC1 = p00[1] * b.w00 + p10[1] * b.w10 + p01[1] * b.w01 + p11[1] * b.w11;
        raC2 = p00[2] * b.w00 + p10[2] * b.w10 + p01[2] * b.w01 + p11[2] * b.w11;
    }

    // cgCoefs = 1D bilinear(tabCgDec, cg) — LDS float2.
    float cgC0, cgC1;
    {
        float u = clamp01(cg) * 95.0f;
        float u0f = floorf(u);
        float fu = u - u0f;
        int u0 = (int)u0f;
        int u1 = min(u0 + 1, 95);
        float2 a = sCgDec[u0];
        float2 b = sCgDec[u1];
        cgC0 = a.x * (1.0f - fu) + b.x * fu;
        cgC1 = a.y * (1.0f - fu) + b.y * fu;
    }

    // vTerm = bilinear(tabLVR tri'd, (nDotLV0*nDotLV1, ra0)) — LDS.
    float vTerm;
    {
        BW b = bw2d<32, 32>(nLV.x * nLV.y, ra0);
        vTerm = sLVR[b.i00] * b.w00 + sLVR[b.i10] * b.w10 +
                sLVR[b.i01] * b.w01 + sLVR[b.i11] * b.w11;
    }

    // nlvCoefs = bilinear(tabLV tri'd, nDotLV) — LDS float4.
    float nlv0, nlv1, nlv2, nlv3;
    {
        BW b = bw2d<32, 32>(nLV.x, nLV.y);
        float4 A = sLV[b.i00], B = sLV[b.i10], C = sLV[b.i01], D = sLV[b.i11];
        nlv0 = A.x * b.w00 + B.x * b.w10 + C.x * b.w01 + D.x * b.w11;
        nlv1 = A.y * b.w00 + B.y * b.w10 + C.y * b.w01 + D.y * b.w11;
        nlv2 = A.z * b.w00 + B.z * b.w10 + C.z * b.w01 + D.z * b.w11;
        nlv3 = A.w * b.w00 + B.w * b.w10 + C.w * b.w01 + D.w * b.w11;
    }

    // nhlCoefs = bilinear(tabNHL tri'd, (metalLoh1, nDotLV0)) — LDS float4.
    float nhl0, nhl1, nhl2, nhl3;
    {
        BW b = bw2d<32, 32>(mL.y, nLV.x);
        float4 A = sNHL[b.i00], B = sNHL[b.i10], C = sNHL[b.i01], D = sNHL[b.i11];
        nhl0 = A.x * b.w00 + B.x * b.w10 + C.x * b.w01 + D.x * b.w11;
        nhl1 = A.y * b.w00 + B.y * b.w10 + C.y * b.w01 + D.y * b.w11;
        nhl2 = A.z * b.w00 + B.z * b.w10 + C.z * b.w01 + D.z * b.w11;
        nhl3 = A.w * b.w00 + B.w * b.w10 + C.w * b.w01 + D.w * b.w11;
    }

    float met = mL.x;
    float om  = 1.0f - met;
    float cd  = om * lC.x;
    float cm0 = sp.x * 0.1f * om * sp.y + met * lC.x;
    float cm1 = sp.x * 0.1f * om * (1.0f - sp.y);
    float cs0 = sh.x * om * sh.y;
    float cs1 = sh.x * om * (1.0f - sh.y);
    float cc  = 0.0625f * lC.y;   // 0.25 * 0.25

    float rsCd0 = rs0 * cd;
    float rsCd1 = rs1 * cd;
    float rsCd2 = rs2 * cd;

    float noh2 = rN.y * rN.y;
    float den  = raC0 * aT.y * aT.y + raC1 * noh2 + raC2;
    float dTerm = 0.25f / (nLV.y * den * den);

    float x = rsCd0 * mL.y * nlv1 + rsCd1 * nlv2 + rsCd2 * nlv3
            + cm0 * vTerm * nhl2 * dTerm + cs0 * nhl0;

    float y = ((1.0f - cm1) * nhl3 + cm1) * vTerm * dTerm
            + cs1 * nhl0
            + cc * nhl1 * nlv0 / (nLV.y * (cgC0 * noh2 + cgC1));

    ((float2*)out)[i] = make_float2(x, y);
}

extern "C" void kernel_launch(void* const* d_in, const int* in_sizes, int n_in,
                              void* d_out, int out_size, void* d_ws, size_t ws_size,
                              hipStream_t stream) {
    // setup_inputs() order:
    // 0 roughNoh, 1 anisoToh, 2 nDotLV, 3 tDotLV (UNUSED), 4 metalLoh,
    // 5 subCg, 6 spst, 7 shst, 8 lumCs,
    // 9 tabRAEnc, 10 tabCgEnc, 11 tabRSEnc, 12 tabRADec, 13 tabCgDec,
    // 14 tabLVR, 15 tabLV, 16 tabNHL
    const float* roughNoh = (const float*)d_in[0];
    const float* anisoToh = (const float*)d_in[1];
    const float* nDotLV   = (const float*)d_in[2];
    const float* metalLoh = (const float*)d_in[4];
    const float* subCg    = (const float*)d_in[5];
    const float* spst     = (const float*)d_in[6];
    const float* shst     = (const float*)d_in[7];
    const float* lumCs    = (const float*)d_in[8];
    const float* tabRAEnc = (const float*)d_in[9];
    const float* tabCgEnc = (const float*)d_in[10];
    const float* tabRSEnc = (const float*)d_in[11];
    const float* tabRADec = (const float*)d_in[12];
    const float* tabCgDec = (const float*)d_in[13];
    const float* tabLVR   = (const float*)d_in[14];
    const float* tabLV    = (const float*)d_in[15];
    const float* tabNHL   = (const float*)d_in[16];

    int n = in_sizes[0] / 2;    // (N,2)
    float* out = (float*)d_out;

    const int block = 1024;
    int grid = (n + block - 1) / block;

    bool use_ws = ws_size >= (size_t)(64 * 64 * sizeof(float4));
    if (use_ws) {
        prep_rs_kernel<<<(64 * 64 + 255) / 256, 256, 0, stream>>>(tabRSEnc, (float4*)d_ws);
        disney_main<true><<<grid, block, 0, stream>>>(
            roughNoh, anisoToh, nDotLV, metalLoh, subCg, spst, shst, lumCs,
            tabRAEnc, tabCgEnc, tabRSEnc, (const float4*)d_ws,
            tabRADec, tabCgDec, tabLVR, tabLV, tabNHL, out, n);
    } else {
        disney_main<false><<<grid, block, 0, stream>>>(
            roughNoh, anisoToh, nDotLV, metalLoh, subCg, spst, shst, lumCs,
            tabRAEnc, tabCgEnc, tabRSEnc, (const float4*)d_ws,
            tabRADec, tabCgDec, tabLVR, tabLV, tabNHL, out, n);
    }
}

// Round 3
// 267.570 us; speedup vs baseline: 1.2152x; 1.0845x over previous
//
#include <hip/hip_runtime.h>
#include <hip/hip_fp16.h>

#define CLIP_HI (1.0f - 1e-6f)

typedef float f4v __attribute__((ext_vector_type(4)));

__device__ __forceinline__ float tri_(float x) {
    return 2.0f * fabsf(x * 0.5f - floorf(x * 0.5f + 0.5f));
}

__device__ __forceinline__ float clamp01(float x) {
    return fminf(fmaxf(x, 0.0f), CLIP_HI);
}

__device__ __forceinline__ float4 nt_load4(const float* p) {
    f4v v = __builtin_nontemporal_load((const f4v*)p);
    return make_float4(v.x, v.y, v.z, v.w);
}
__device__ __forceinline__ void nt_store4(float* p, float4 v) {
    f4v t = {v.x, v.y, v.z, v.w};
    __builtin_nontemporal_store(t, (f4v*)p);
}

// 8-byte half4 payload: one ds_read_b64 / global_load_dwordx2 per sample.
struct H4 { __half2 xy, zw; };

struct BW {
    int i00, i10, i01, i11;
    float w00, w10, w01, w11;
};

template <int U, int V>
__device__ __forceinline__ BW bw2d(float uc, float vc) {
    float u = clamp01(uc) * (float)(U - 1);
    float v = clamp01(vc) * (float)(V - 1);
    float u0f = floorf(u), v0f = floorf(v);
    float fu = u - u0f, fv = v - v0f;
    int u0 = (int)u0f, v0 = (int)v0f;
    int u1 = min(u0 + 1, U - 1);
    int v1 = min(v0 + 1, V - 1);
    BW r;
    r.i00 = u0 * V + v0;
    r.i10 = u1 * V + v0;
    r.i01 = u0 * V + v1;
    r.i11 = u1 * V + v1;
    float gu = 1.0f - fu, gv = 1.0f - fv;
    r.w00 = gu * gv; r.w10 = fu * gv; r.w01 = gu * fv; r.w11 = fu * fv;
    return r;
}

__device__ __forceinline__ float4 h4_blend(H4 A, H4 B, H4 C, H4 D, const BW& b) {
    float2 Axy = __half22float2(A.xy), Azw = __half22float2(A.zw);
    float2 Bxy = __half22float2(B.xy), Bzw = __half22float2(B.zw);
    float2 Cxy = __half22float2(C.xy), Czw = __half22float2(C.zw);
    float2 Dxy = __half22float2(D.xy), Dzw = __half22float2(D.zw);
    return make_float4(
        Axy.x * b.w00 + Bxy.x * b.w10 + Cxy.x * b.w01 + Dxy.x * b.w11,
        Axy.y * b.w00 + Bxy.y * b.w10 + Cxy.y * b.w01 + Dxy.y * b.w11,
        Azw.x * b.w00 + Bzw.x * b.w10 + Czw.x * b.w01 + Dzw.x * b.w11,
        Azw.y * b.w00 + Bzw.y * b.w10 + Czw.y * b.w01 + Dzw.y * b.w11);
}

// Prep: tabRSEnc (64,64,3) -> (64,64) half4 in d_ws, tri() applied. 32 KB.
__global__ __launch_bounds__(256) void prep_rs_kernel(const float* __restrict__ t,
                                                      H4* __restrict__ o) {
    int j = blockIdx.x * 256 + threadIdx.x;
    if (j < 64 * 64) {
        float a = tri_(t[j * 3 + 0]);
        float b = tri_(t[j * 3 + 1]);
        float c = tri_(t[j * 3 + 2]);
        H4 h;
        h.xy = __floats2half2_rn(a, b);
        h.zw = __floats2half2_rn(c, 0.0f);
        o[j] = h;
    }
}

// Per-element core. Streams passed as scalars; tables via LDS/global pointers.
template <bool USE_WS>
__device__ __forceinline__ float2 shade(
    float rNx, float rNy, float aTx, float aTy, float nLVx, float nLVy,
    float mLx, float mLy, float sCx, float sCy, float spx, float spy,
    float shx, float shy, float lCx, float lCy,
    const float* __restrict__ tabRAEnc, const float* __restrict__ tabRSEnc,
    const H4* __restrict__ rsPacked,
    const float* sRADec, const float2* sCgDec, const float* sCgEnc,
    const float* sLVR, const H4* sLV, const H4* sNHL)
{
    // --- independent global gather #1: tabRAEnc nearest (33.5 MB) ---
    int ui = (int)rintf(clamp01(rNx) * 2047.0f);   // jnp.round = half-to-even
    int vi = (int)rintf(clamp01(aTx) * 2047.0f);
    float2 raT = ((const float2*)tabRAEnc)[ui * 2048 + vi];

    // --- independent gathers: rsEnc bilinear ---
    float rs0, rs1, rs2;
    {
        BW b = bw2d<64, 64>(rNx, sCx);
        if constexpr (USE_WS) {
            float4 r = h4_blend(rsPacked[b.i00], rsPacked[b.i10],
                                rsPacked[b.i01], rsPacked[b.i11], b);
            rs0 = r.x; rs1 = r.y; rs2 = r.z;
        } else {
            const float* p00 = tabRSEnc + b.i00 * 3;
            const float* p10 = tabRSEnc + b.i10 * 3;
            const float* p01 = tabRSEnc + b.i01 * 3;
            const float* p11 = tabRSEnc + b.i11 * 3;
            rs0 = tri_(p00[0]) * b.w00 + tri_(p10[0]) * b.w10 + tri_(p01[0]) * b.w01 + tri_(p11[0]) * b.w11;
            rs1 = tri_(p00[1]) * b.w00 + tri_(p10[1]) * b.w10 + tri_(p01[1]) * b.w01 + tri_(p11[1]) * b.w11;
            rs2 = tri_(p00[2]) * b.w00 + tri_(p10[2]) * b.w10 + tri_(p01[2]) * b.w01 + tri_(p11[2]) * b.w11;
        }
    }

    // --- cg (LDS, tri folded) -> cgCoefs (LDS fp32, denominator-critical) ---
    float cgC0, cgC1;
    {
        float cg = sCgEnc[(int)rintf(clamp01(sCy) * 2047.0f)];
        float u = clamp01(cg) * 95.0f;
        float u0f = floorf(u);
        float fu = u - u0f;
        int u0 = (int)u0f;
        int u1 = min(u0 + 1, 95);
        float2 a = sCgDec[u0];
        float2 b = sCgDec[u1];
        cgC0 = a.x * (1.0f - fu) + b.x * fu;
        cgC1 = a.y * (1.0f - fu) + b.y * fu;
    }

    // --- nlv, nhl (LDS half4) ---
    float4 nlv, nhl;
    {
        BW b = bw2d<32, 32>(nLVx, nLVy);
        nlv = h4_blend(sLV[b.i00], sLV[b.i10], sLV[b.i01], sLV[b.i11], b);
    }
    {
        BW b = bw2d<32, 32>(mLy, nLVx);
        nhl = h4_blend(sNHL[b.i00], sNHL[b.i10], sNHL[b.i01], sNHL[b.i11], b);
    }

    // --- dependent on RAEnc gather: ra -> raCoefs (fp32 LDS), vTerm ---
    float ra0 = tri_(raT.x);
    float ra1 = tri_(raT.y);

    float raC0, raC1, raC2;
    {
        BW b = bw2d<48, 48>(ra0, ra1);
        const float* p00 = &sRADec[b.i00 * 3];
        const float* p10 = &sRADec[b.i10 * 3];
        const float* p01 = &sRADec[b.i01 * 3];
        const float* p11 = &sRADec[b.i11 * 3];
        raC0 = p00[0] * b.w00 + p10[0] * b.w10 + p01[0] * b.w01 + p11[0] * b.w11;
        raC1 = p00[1] * b.w00 + p10[1] * b.w10 + p01[1] * b.w01 + p11[1] * b.w11;
        raC2 = p00[2] * b.w00 + p10[2] * b.w10 + p01[2] * b.w01 + p11[2] * b.w11;
    }

    float vTerm;
    {
        BW b = bw2d<32, 32>(nLVx * nLVy, ra0);
        vTerm = sLVR[b.i00] * b.w00 + sLVR[b.i10] * b.w10 +
                sLVR[b.i01] * b.w01 + sLVR[b.i11] * b.w11;
    }

    // --- epilogue arithmetic ---
    float met = mLx;
    float om  = 1.0f - met;
    float cd  = om * lCx;
    float cm0 = spx * 0.1f * om * spy + met * lCx;
    float cm1 = spx * 0.1f * om * (1.0f - spy);
    float cs0 = shx * om * shy;
    float cs1 = shx * om * (1.0f - shy);
    float cc  = 0.0625f * lCy;

    float noh2 = rNy * rNy;
    float den  = raC0 * aTy * aTy + raC1 * noh2 + raC2;
    float dTerm = 0.25f / (nLVy * den * den);

    float x = rs0 * cd * mLy * nlv.y + rs1 * cd * nlv.z + rs2 * cd * nlv.w
            + cm0 * vTerm * nhl.z * dTerm + cs0 * nhl.x;

    float y = ((1.0f - cm1) * nhl.w + cm1) * vTerm * dTerm
            + cs1 * nhl.x
            + cc * nhl.y * nlv.x / (nLVy * (cgC0 * noh2 + cgC1));

    return make_float2(x, y);
}

template <bool USE_WS>
__global__ __launch_bounds__(1024, 8) void disney_main(
    const float* __restrict__ roughNoh,
    const float* __restrict__ anisoToh,
    const float* __restrict__ nDotLV,
    const float* __restrict__ metalLoh,
    const float* __restrict__ subCg,
    const float* __restrict__ spst,
    const float* __restrict__ shst,
    const float* __restrict__ lumCs,
    const float* __restrict__ tabRAEnc,   // (2048,2048,2) global gather
    const float* __restrict__ tabCgEnc,   // (2048,1)  -> LDS (tri'd)
    const float* __restrict__ tabRSEnc,   // (64,64,3) fallback path
    const H4*    __restrict__ rsPacked,   // (64,64) half4 in d_ws, tri'd
    const float* __restrict__ tabRADec,   // (48,48,3) -> LDS fp32
    const float* __restrict__ tabCgDec,   // (96,2)    -> LDS fp32
    const float* __restrict__ tabLVR,     // (32,32,1) -> LDS fp32 (tri'd)
    const float* __restrict__ tabLV,      // (32,32,4) -> LDS half4 (tri'd)
    const float* __restrict__ tabNHL,     // (32,32,4) -> LDS half4 (tri'd)
    float* __restrict__ out,
    int n)
{
    // 57088 B: 2 blocks/CU (114 KiB of 160 KiB) -> 32 waves/CU.
    __shared__ float  sRADec[48 * 48 * 3];   // 27648 B (denominator-critical)
    __shared__ float2 sCgDec[96];            //   768 B (denominator-critical)
    __shared__ float  sCgEnc[2048];          //  8192 B
    __shared__ float  sLVR[1024];            //  4096 B
    __shared__ H4     sLV[1024];             //  8192 B
    __shared__ H4     sNHL[1024];            //  8192 B

    int tid = threadIdx.x;

    for (int j = tid; j < 48 * 48 * 3; j += 1024) sRADec[j] = tabRADec[j];
    if (tid < 96) sCgDec[tid] = ((const float2*)tabCgDec)[tid];
    sCgEnc[tid]        = tri_(tabCgEnc[tid]);
    sCgEnc[tid + 1024] = tri_(tabCgEnc[tid + 1024]);
    sLVR[tid] = tri_(tabLVR[tid]);
    {
        float4 v = ((const float4*)tabLV)[tid];
        H4 h; h.xy = __floats2half2_rn(tri_(v.x), tri_(v.y));
              h.zw = __floats2half2_rn(tri_(v.z), tri_(v.w));
        sLV[tid] = h;
    }
    {
        float4 v = ((const float4*)tabNHL)[tid];
        H4 h; h.xy = __floats2half2_rn(tri_(v.x), tri_(v.y));
              h.zw = __floats2half2_rn(tri_(v.z), tri_(v.w));
        sNHL[tid] = h;
    }
    __syncthreads();

    // pair index: this thread owns elements 2p and 2p+1 (adjacent -> float4 streams)
    int p = blockIdx.x * 1024 + tid;
    int e0 = 2 * p;
    if (e0 >= n) return;
    bool has2 = (e0 + 1) < n;

    // non-temporal: touch-once streams, keep L2/L3 for tabRAEnc
    float4 rN  = nt_load4(roughNoh + 4 * p);
    float4 aT  = nt_load4(anisoToh + 4 * p);
    float4 nLV = nt_load4(nDotLV   + 4 * p);
    float4 mL  = nt_load4(metalLoh + 4 * p);
    float4 sC  = nt_load4(subCg    + 4 * p);
    float4 sp  = nt_load4(spst     + 4 * p);
    float4 sh  = nt_load4(shst     + 4 * p);
    float4 lC  = nt_load4(lumCs    + 4 * p);

    float2 r0 = shade<USE_WS>(rN.x, rN.y, aT.x, aT.y, nLV.x, nLV.y,
                              mL.x, mL.y, sC.x, sC.y, sp.x, sp.y,
                              sh.x, sh.y, lC.x, lC.y,
                              tabRAEnc, tabRSEnc, rsPacked,
                              sRADec, sCgDec, sCgEnc, sLVR, sLV, sNHL);
    if (has2) {
        float2 r1 = shade<USE_WS>(rN.z, rN.w, aT.z, aT.w, nLV.z, nLV.w,
                                  mL.z, mL.w, sC.z, sC.w, sp.z, sp.w,
                                  sh.z, sh.w, lC.z, lC.w,
                                  tabRAEnc, tabRSEnc, rsPacked,
                                  sRADec, sCgDec, sCgEnc, sLVR, sLV, sNHL);
        nt_store4(out + 4 * p, make_float4(r0.x, r0.y, r1.x, r1.y));
    } else {
        ((float2*)out)[e0] = r0;
    }
}

extern "C" void kernel_launch(void* const* d_in, const int* in_sizes, int n_in,
                              void* d_out, int out_size, void* d_ws, size_t ws_size,
                              hipStream_t stream) {
    // 0 roughNoh, 1 anisoToh, 2 nDotLV, 3 tDotLV (UNUSED), 4 metalLoh,
    // 5 subCg, 6 spst, 7 shst, 8 lumCs, 9 tabRAEnc, 10 tabCgEnc, 11 tabRSEnc,
    // 12 tabRADec, 13 tabCgDec, 14 tabLVR, 15 tabLV, 16 tabNHL
    const float* roughNoh = (const float*)d_in[0];
    const float* anisoToh = (const float*)d_in[1];
    const float* nDotLV   = (const float*)d_in[2];
    const float* metalLoh = (const float*)d_in[4];
    const float* subCg    = (const float*)d_in[5];
    const float* spst     = (const float*)d_in[6];
    const float* shst     = (const float*)d_in[7];
    const float* lumCs    = (const float*)d_in[8];
    const float* tabRAEnc = (const float*)d_in[9];
    const float* tabCgEnc = (const float*)d_in[10];
    const float* tabRSEnc = (const float*)d_in[11];
    const float* tabRADec = (const float*)d_in[12];
    const float* tabCgDec = (const float*)d_in[13];
    const float* tabLVR   = (const float*)d_in[14];
    const float* tabLV    = (const float*)d_in[15];
    const float* tabNHL   = (const float*)d_in[16];

    int n = in_sizes[0] / 2;   // (N,2)
    float* out = (float*)d_out;

    const int block = 1024;
    int pairs = (n + 1) / 2;
    int grid = (pairs + block - 1) / block;

    bool use_ws = ws_size >= (size_t)(64 * 64 * sizeof(H4));
    if (use_ws) {
        prep_rs_kernel<<<(64 * 64 + 255) / 256, 256, 0, stream>>>(tabRSEnc, (H4*)d_ws);
        disney_main<true><<<grid, block, 0, stream>>>(
            roughNoh, anisoToh, nDotLV, metalLoh, subCg, spst, shst, lumCs,
            tabRAEnc, tabCgEnc, tabRSEnc, (const H4*)d_ws,
            tabRADec, tabCgDec, tabLVR, tabLV, tabNHL, out, n);
    } else {
        disney_main<false><<<grid, block, 0, stream>>>(
            roughNoh, anisoToh, nDotLV, metalLoh, subCg, spst, shst, lumCs,
            tabRAEnc, tabCgEnc, tabRSEnc, (const H4*)d_ws,
            tabRADec, tabCgDec, tabLVR, tabLV, tabNHL, out, n);
    }
}